// Round 6
// baseline (210.079 us; speedup 1.0000x reference)
//
#include <hip/hip_runtime.h>
#include <hip/hip_bf16.h>

typedef __bf16 bf16x8 __attribute__((ext_vector_type(8)));
typedef float f32x4 __attribute__((ext_vector_type(4)));

#define NROWS 8192
#define HALF_N 4096
#define DIM 128
#define ROW_BYTES 256            /* 128 bf16 */
#define C1 14.42695040888963f    /* (1/T) * log2(e) */
#define LN2 0.6931471805599453f
#define NBLK 512                 /* 64 row-groups x 8 col-splits */
#define CS_COLS 1024
#define STAGE_COLS 64
#define ITERS 16                 /* 1024 / 64 */

/* rn/rnA stored globally swizzled: 16B chunk kc of row r at r*256+(kc^(r&7))*16.
   global_load_lds copies verbatim; all tile bases are 0 mod 8 so local swizzle
   equals global. rnA = rn * C1 so MFMA outputs s*C1 directly (saves one VALU
   op per exp element; fixups folded into finalize's log identity). */
#define SWZ(r, kc) ((kc) ^ ((r) & 7))

__global__ __launch_bounds__(256, 2) void k_fused(
    const float* __restrict__ zi, const float* __restrict__ zj,
    char* __restrict__ rn, char* __restrict__ rnA,
    float* __restrict__ rowsum, float* __restrict__ pbuf,
    unsigned int* __restrict__ flag, unsigned int* __restrict__ done,
    float* __restrict__ out)
{
    __shared__ char lds_b[2][STAGE_COLS * ROW_BYTES];   // 2 x 16 KB
    const int tid  = threadIdx.x;
    const int wave = tid >> 6;
    const int lane = tid & 63;
    const int rg = blockIdx.x >> 3;      // 64 row-groups of 128 rows
    const int cs = blockIdx.x & 7;       // 8 col-splits of 1024 cols
    const int w0 = wave & 1, w1 = wave >> 1;
    const int qrow = lane >> 4, lcol = lane & 15;

    // ===== phase 0: normalize rows [blk*16,+16) via agent-coherent stores ====
    #pragma unroll
    for (int i = 0; i < 4; ++i) {
        const int row = blockIdx.x * 16 + wave * 4 + i;
        const float* src = (row < HALF_N) ? (zi + (size_t)row * DIM)
                                          : (zj + (size_t)(row - HALF_N) * DIM);
        float2 v = *(const float2*)(src + lane * 2);
        float ss = v.x * v.x + v.y * v.y;
        #pragma unroll
        for (int m = 32; m >= 1; m >>= 1) ss += __shfl_xor(ss, m, 64);
        const float sc = 1.0f / fmaxf(sqrtf(ss), 1e-8f);
        union { __bf16 h[2]; unsigned u; } a, b;
        a.h[0] = (__bf16)(v.x * sc);      a.h[1] = (__bf16)(v.y * sc);
        b.h[0] = (__bf16)(v.x * sc * C1); b.h[1] = (__bf16)(v.y * sc * C1);
        const size_t off = (size_t)row * ROW_BYTES + SWZ(row, lane >> 2) * 16 + (lane & 3) * 4;
        __hip_atomic_store((unsigned*)(rn  + off), a.u, __ATOMIC_RELAXED, __HIP_MEMORY_SCOPE_AGENT);
        __hip_atomic_store((unsigned*)(rnA + off), b.u, __ATOMIC_RELAXED, __HIP_MEMORY_SCOPE_AGENT);
    }
    if (tid < 16)   // zero own rowsum slice before publishing
        __hip_atomic_store((unsigned*)&rowsum[blockIdx.x * 16 + tid], 0u,
                           __ATOMIC_RELAXED, __HIP_MEMORY_SCOPE_AGENT);
    __syncthreads();
    if (tid == 0)
        __hip_atomic_store(&flag[blockIdx.x], 1u, __ATOMIC_RELEASE, __HIP_MEMORY_SCOPE_AGENT);

    // ===== wait for the 8 A-producer + 64 B-producer blocks we consume ======
    {
        const unsigned* fA = &flag[rg * 8 + (lane & 7)];
        const unsigned* fB = &flag[cs * 64 + lane];
        int spins = 0;
        for (;;) {
            unsigned a = __hip_atomic_load(fA, __ATOMIC_ACQUIRE, __HIP_MEMORY_SCOPE_AGENT);
            unsigned b = __hip_atomic_load(fB, __ATOMIC_ACQUIRE, __HIP_MEMORY_SCOPE_AGENT);
            if (__ballot(a && b) == ~0ull) break;
            __builtin_amdgcn_s_sleep(8);
            if (++spins > (1 << 20)) break;   // bounded escape hatch (no hang)
        }
        __threadfence();   // invalidate caches before reading rn/rnA
    }

    // ===== phase 1: 128-row x 1024-col GEMM, 16 stages of 64 cols ===========
    auto stage_b = [&](int s) {
        const char* g = rn + ((size_t)cs * CS_COLS + s * STAGE_COLS) * ROW_BYTES;
        #pragma unroll
        for (int i = 0; i < 4; ++i) {
            const int off = wave * 4096 + i * 1024;
            __builtin_amdgcn_global_load_lds(
                (const __attribute__((address_space(1))) void*)(g + off + lane * 16),
                (__attribute__((address_space(3))) void*)(&lds_b[s & 1][off]),
                16, 0, 0);
        }
    };

    stage_b(0);                                // 4 outstanding
    bf16x8 afrag[4][4];                        // A rows in regs, from rnA (s*C1)
    #pragma unroll
    for (int mi = 0; mi < 4; ++mi) {
        const int m = rg * 128 + w1 * 64 + mi * 16 + lcol;
        #pragma unroll
        for (int ks = 0; ks < 4; ++ks)
            afrag[mi][ks] = *(const bf16x8*)(rnA + (size_t)m * ROW_BYTES
                                             + SWZ(m, ks * 4 + qrow) * 16);
    }                                          // +16
    stage_b(1);                                // +4 -> 24 outstanding

    // positive band: rows rg*128+o  ->  col pcol0+o  (o in [0,128), no wrap)
    const int pcol0 = (rg * 128 + HALF_N) & (NROWS - 1);
    const int s_p = (pcol0 >= cs * CS_COLS && pcol0 < cs * CS_COLS + CS_COLS)
                        ? (pcol0 - cs * CS_COLS) / STAGE_COLS : -999;

    float rsum[4][4];
    #pragma unroll
    for (int mi = 0; mi < 4; ++mi)
        #pragma unroll
        for (int r = 0; r < 4; ++r) rsum[mi][r] = 0.0f;

    #pragma unroll 1
    for (int it = 0; it < ITERS; ++it) {
        if (it == ITERS - 1)
            asm volatile("s_waitcnt vmcnt(0)\n\ts_barrier" ::: "memory");
        else
            asm volatile("s_waitcnt vmcnt(4)\n\ts_barrier" ::: "memory");

        f32x4 acc[4][2];
        const f32x4 zero = {0.0f, 0.0f, 0.0f, 0.0f};
        #pragma unroll
        for (int mi = 0; mi < 4; ++mi) { acc[mi][0] = zero; acc[mi][1] = zero; }

        #pragma unroll
        for (int ks = 0; ks < 4; ++ks) {
            bf16x8 bfrag[2];
            #pragma unroll
            for (int ni = 0; ni < 2; ++ni) {
                const int n = w0 * 32 + ni * 16 + lcol;
                bfrag[ni] = *(const bf16x8*)(&lds_b[it & 1][n * ROW_BYTES
                                             + SWZ(n, ks * 4 + qrow) * 16]);
            }
            #pragma unroll
            for (int mi = 0; mi < 4; ++mi)
                #pragma unroll
                for (int ni = 0; ni < 2; ++ni)
                    acc[mi][ni] = __builtin_amdgcn_mfma_f32_16x16x32_bf16(
                        afrag[mi][ks], bfrag[ni], acc[mi][ni], 0, 0, 0);
        }

        asm volatile("s_barrier" ::: "memory");   // all waves done with lds_b[p]
        if (it + 2 < ITERS) stage_b(it + 2);      // refill flies over epilogue

        if (it == s_p || it == s_p + 1) {         // extract positives (s*C1)
            const int h = it - s_p;
            if (w1 == h) {
                #pragma unroll
                for (int mi = 0; mi < 4; ++mi) {
                    const int o64 = mi * 16 + qrow * 4;
                    #pragma unroll
                    for (int ni = 0; ni < 2; ++ni)
                        #pragma unroll
                        for (int rr = 0; rr < 4; ++rr)
                            if (o64 + rr == w0 * 32 + ni * 16 + lcol)
                                __hip_atomic_store(&pbuf[rg * 128 + h * 64 + o64 + rr],
                                                   acc[mi][ni][rr],
                                                   __ATOMIC_RELAXED, __HIP_MEMORY_SCOPE_AGENT);
                }
            }
        }

        // rowsum += 2^(s*C1)  (no shift needed: terms <= 2^14.43, sum < 2e8)
        #pragma unroll
        for (int mi = 0; mi < 4; ++mi)
            #pragma unroll
            for (int ni = 0; ni < 2; ++ni)
                #pragma unroll
                for (int r = 0; r < 4; ++r)
                    rsum[mi][r] += __builtin_amdgcn_exp2f(acc[mi][ni][r]);
    }

    #pragma unroll
    for (int mi = 0; mi < 4; ++mi)
        #pragma unroll
        for (int r = 0; r < 4; ++r) {
            float v = rsum[mi][r];
            v += __shfl_xor(v, 1, 64);
            v += __shfl_xor(v, 2, 64);
            v += __shfl_xor(v, 4, 64);
            v += __shfl_xor(v, 8, 64);
            if (lcol == 0)
                atomicAdd(&rowsum[rg * 128 + w1 * 64 + mi * 16 + qrow * 4 + r], v);
        }

    // ===== last-block finalize (round-3/4-verified protocol) ================
    __syncthreads();
    __shared__ int is_last;
    if (tid == 0) {
        __threadfence();
        unsigned old = __hip_atomic_fetch_add(done, 1u, __ATOMIC_ACQ_REL,
                                              __HIP_MEMORY_SCOPE_AGENT);
        is_last = (old == NBLK - 1);
    }
    __syncthreads();
    if (!is_last) return;
    __threadfence();

    // loss_k = ln(denom) - p/T = (log2(rowsum + 2^(p*C1)) - p*C1) * ln2
    float lsum = 0.0f;
    for (int r = tid; r < NROWS; r += 256) {
        float rs = __hip_atomic_load(&rowsum[r], __ATOMIC_RELAXED, __HIP_MEMORY_SCOPE_AGENT);
        float pv = __hip_atomic_load(&pbuf[r],   __ATOMIC_RELAXED, __HIP_MEMORY_SCOPE_AGENT);
        float S  = rs + __builtin_amdgcn_exp2f(pv);
        lsum += (__builtin_amdgcn_logf(S) - pv) * LN2;
    }
    #pragma unroll
    for (int m = 32; m >= 1; m >>= 1) lsum += __shfl_xor(lsum, m, 64);
    __shared__ float part[4];
    if (lane == 0) part[wave] = lsum;
    __syncthreads();
    if (tid == 0)
        out[0] = (part[0] + part[1] + part[2] + part[3]) * (1.0f / (float)NROWS);
}

extern "C" void kernel_launch(void* const* d_in, const int* in_sizes, int n_in,
                              void* d_out, int out_size, void* d_ws, size_t ws_size,
                              hipStream_t stream)
{
    const float* zi = (const float*)d_in[0];
    const float* zj = (const float*)d_in[1];
    float* out = (float*)d_out;

    // ws: rn 2MB | rnA 2MB | rowsum 32KB | pbuf 32KB | flag[512]+done
    char*  rn     = (char*)d_ws;
    char*  rnA    = rn + (size_t)NROWS * ROW_BYTES;
    float* rowsum = (float*)(rnA + (size_t)NROWS * ROW_BYTES);
    float* pbuf   = rowsum + NROWS;
    unsigned int* flag = (unsigned int*)(pbuf + NROWS);
    unsigned int* done = flag + NBLK;

    hipMemsetAsync(flag, 0, (NBLK + 1) * sizeof(unsigned int), stream);
    k_fused<<<NBLK, 256, 0, stream>>>(zi, zj, rn, rnA, rowsum, pbuf, flag, done, out);
}

// Round 8
// 102.939 us; speedup vs baseline: 2.0408x; 2.0408x over previous
//
#include <hip/hip_runtime.h>
#include <hip/hip_bf16.h>

typedef __bf16 bf16x8 __attribute__((ext_vector_type(8)));
typedef __bf16 bf16x2 __attribute__((ext_vector_type(2)));
typedef float f32x4 __attribute__((ext_vector_type(4)));

#define NROWS 8192
#define HALF_N 4096
#define DIM 128
#define ROW_BYTES 256            /* 128 bf16, plain row-major */
#define C1 14.42695040888963f    /* (1/T) * log2(e) */
#define LN2 0.6931471805599453f

// ---------------- kernel 1: row-normalize -> rn (plain) and rnA (= rn*C1) ---
// rnA pre-scales the A operand so MFMA outputs s*C1 directly; the exp epilogue
// is then exp2(acc) with no per-element fixup (validated rounds 5/6, absmax 0).
__global__ __launch_bounds__(256) void k_normalize(
    const float* __restrict__ zi, const float* __restrict__ zj,
    char* __restrict__ rn, char* __restrict__ rnA, float* __restrict__ rowsum)
{
    const int wave = threadIdx.x >> 6;
    const int lane = threadIdx.x & 63;
    #pragma unroll
    for (int i = 0; i < 4; ++i) {
        const int row = blockIdx.x * 16 + wave * 4 + i;
        const float* src = (row < HALF_N) ? (zi + (size_t)row * DIM)
                                          : (zj + (size_t)(row - HALF_N) * DIM);
        float2 v = *(const float2*)(src + lane * 2);
        float ss = v.x * v.x + v.y * v.y;
        #pragma unroll
        for (int m = 32; m >= 1; m >>= 1) ss += __shfl_xor(ss, m, 64);
        const float sc = 1.0f / fmaxf(sqrtf(ss), 1e-8f);
        bf16x2 a, b;
        a[0] = (__bf16)(v.x * sc);      a[1] = (__bf16)(v.y * sc);
        b[0] = (__bf16)(v.x * sc * C1); b[1] = (__bf16)(v.y * sc * C1);
        *(bf16x2*)(rn  + (size_t)row * ROW_BYTES + lane * 4) = a;
        *(bf16x2*)(rnA + (size_t)row * ROW_BYTES + lane * 4) = b;
    }
    if (threadIdx.x < 16) rowsum[blockIdx.x * 16 + threadIdx.x] = 0.0f;
}

// ---------------- kernel 2: wave-independent sim GEMM + exp rowsum ----------
// NO LDS, NO barriers, NO hand waitcnts (rounds 1-6: every barrier-coupled /
// asm-scheduled variant stalled ~70-95%). Each wave independently computes a
// 64-row x 512-col strip: A-frags (16 x bf16x8 = 64 VGPR) held in registers,
// B streamed 16 cols/step via plain global_load_dwordx4 (compiler-scheduled).
// Latency hidden by many independent waves/CU, not intra-block pipelines.
// The 4 waves of a block share the same col range -> L1 reuse of B lines.
__global__ __launch_bounds__(256) void k_gemm(
    const char* __restrict__ rn, const char* __restrict__ rnA,
    float* __restrict__ rowsum)
{
    const int wave = threadIdx.x >> 6;
    const int lane = threadIdx.x & 63;
    const int qrow = lane >> 4, lcol = lane & 15;
    const int cv = blockIdx.x & 15;                   // 16 col-splits of 512
    const int rg = (blockIdx.x >> 4) * 4 + wave;      // 128 row-groups of 64

    // A fragments: rows [rg*64, +64) from rnA, all K. m = mi*16+lcol,
    // k-chunk = ks*32 + qrow*8 -> byte ks*64 + qrow*16.
    const char* Ab = rnA + (size_t)(rg * 64) * ROW_BYTES;
    bf16x8 afrag[4][4];
    #pragma unroll
    for (int mi = 0; mi < 4; ++mi)
        #pragma unroll
        for (int ks = 0; ks < 4; ++ks)
            afrag[mi][ks] = *(const bf16x8*)(Ab + (mi * 16 + lcol) * ROW_BYTES
                                             + ks * 64 + qrow * 16);

    float rsum[4][4];
    #pragma unroll
    for (int mi = 0; mi < 4; ++mi)
        #pragma unroll
        for (int r = 0; r < 4; ++r) rsum[mi][r] = 0.0f;

    const char* Bb = rn + (size_t)(cv * 512) * ROW_BYTES + lcol * ROW_BYTES + qrow * 16;

    #pragma unroll 1
    for (int s = 0; s < 32; ++s) {                    // 32 steps of 16 cols
        const char* bp = Bb + s * 16 * ROW_BYTES;
        bf16x8 bfrag[4];
        #pragma unroll
        for (int ks = 0; ks < 4; ++ks)
            bfrag[ks] = *(const bf16x8*)(bp + ks * 64);

        f32x4 acc[4];
        const f32x4 zero = {0.0f, 0.0f, 0.0f, 0.0f};
        #pragma unroll
        for (int mi = 0; mi < 4; ++mi) acc[mi] = zero;
        #pragma unroll
        for (int ks = 0; ks < 4; ++ks)
            #pragma unroll
            for (int mi = 0; mi < 4; ++mi)
                acc[mi] = __builtin_amdgcn_mfma_f32_16x16x32_bf16(
                    afrag[mi][ks], bfrag[ks], acc[mi], 0, 0, 0);

        // rowsum += 2^(s*C1); acc already holds s*C1 via pre-scaled A
        #pragma unroll
        for (int mi = 0; mi < 4; ++mi)
            #pragma unroll
            for (int r = 0; r < 4; ++r)
                rsum[mi][r] += __builtin_amdgcn_exp2f(acc[mi][r]);
    }

    // reduce over the 16 col-lanes, one atomic per row (4 adders per addr)
    #pragma unroll
    for (int mi = 0; mi < 4; ++mi)
        #pragma unroll
        for (int r = 0; r < 4; ++r) {
            float v = rsum[mi][r];
            v += __shfl_xor(v, 1, 64);
            v += __shfl_xor(v, 2, 64);
            v += __shfl_xor(v, 4, 64);
            v += __shfl_xor(v, 8, 64);
            if (lcol == 0)
                atomicAdd(&rowsum[rg * 64 + mi * 16 + qrow * 4 + r], v);
        }
}

// ---------------- kernel 3: per-row loss (no atomics) -----------------------
// p_k from a fresh bf16 dot (f32 accum).
// v_log_f32 is LOG2: loss_k = (log2(rowsum + 2^(p*C1)) - p*C1) * ln2
// (round-7 bug: LN2 was applied to only the pc term — error was exactly
//  log2(S)*(1-ln2) ≈ 4.625, matching the harness report)
__global__ __launch_bounds__(256) void k_rowloss(
    const char* __restrict__ rn, const float* __restrict__ rowsum,
    float* __restrict__ row_loss)
{
    const int row  = blockIdx.x * 4 + (threadIdx.x >> 6);
    const int lane = threadIdx.x & 63;
    const int partner = (row + HALF_N) & (NROWS - 1);
    const bf16x2 a = *(const bf16x2*)(rn + (size_t)row * ROW_BYTES + lane * 4);
    const bf16x2 b = *(const bf16x2*)(rn + (size_t)partner * ROW_BYTES + lane * 4);
    float p = (float)a[0] * (float)b[0] + (float)a[1] * (float)b[1];
    #pragma unroll
    for (int m = 32; m >= 1; m >>= 1) p += __shfl_xor(p, m, 64);
    if (lane == 0) {
        const float pc = p * C1;
        const float S  = rowsum[row] + __builtin_amdgcn_exp2f(pc);
        row_loss[row] = (__builtin_amdgcn_logf(S) - pc) * LN2;
    }
}

// ---------------- kernel 4: single-block reduce -> out ----------------------
__global__ __launch_bounds__(256) void k_reduce(
    const float* __restrict__ row_loss, float* __restrict__ out)
{
    const f32x4* v4 = (const f32x4*)row_loss;
    float s = 0.0f;
    for (int i = threadIdx.x; i < NROWS / 4; i += 256) {
        f32x4 v = v4[i];
        s += (v[0] + v[1]) + (v[2] + v[3]);
    }
    #pragma unroll
    for (int m = 32; m >= 1; m >>= 1) s += __shfl_xor(s, m, 64);
    __shared__ float part[4];
    if ((threadIdx.x & 63) == 0) part[threadIdx.x >> 6] = s;
    __syncthreads();
    if (threadIdx.x == 0)
        out[0] = (part[0] + part[1] + part[2] + part[3]) * (1.0f / (float)NROWS);
}

extern "C" void kernel_launch(void* const* d_in, const int* in_sizes, int n_in,
                              void* d_out, int out_size, void* d_ws, size_t ws_size,
                              hipStream_t stream)
{
    const float* zi = (const float*)d_in[0];
    const float* zj = (const float*)d_in[1];
    float* out = (float*)d_out;

    // ws: rn 2MB | rnA 2MB | rowsum f32[8192] | row_loss f32[8192]
    char*  rn       = (char*)d_ws;
    char*  rnA      = rn + (size_t)NROWS * ROW_BYTES;
    float* rowsum   = (float*)(rnA + (size_t)NROWS * ROW_BYTES);
    float* row_loss = rowsum + NROWS;

    k_normalize<<<NROWS / 16, 256, 0, stream>>>(zi, zj, rn, rnA, rowsum);
    k_gemm<<<512, 256, 0, stream>>>(rn, rnA, rowsum);
    k_rowloss<<<NROWS / 4, 256, 0, stream>>>(rn, rowsum, row_loss);
    k_reduce<<<1, 256, 0, stream>>>(row_loss, out);
}